// Round 9
// baseline (3348.685 us; speedup 1.0000x reference)
//
#include <hip/hip_runtime.h>
#include <math.h>

// hipcc defaults to -ffp-contract=fast; contraction would fuse mul+add into
// FMA and break bit-exactness vs XLA. Scalar helpers use __fmul_rn/__fadd_rn.
#pragma clang fp contract(off)

#define NSTEPS 3000
#define NWALK  1048576
#define BLOCK  256
#define NBP    1536     // 6 blocks/CU x 256 CU (24KB LDS -> 6 resident): 1 cohort
#define NSTATIC (NBP * BLOCK)
#define KREFILL 8       // steps between refill checks: ~4% dead-lane waste

__device__ uint32_t g_pool;

__global__ void init_kernel() { g_pool = NSTATIC; }

// Threefry-2x32, 20 rounds, exactly JAX's schedule.
__device__ __forceinline__ void tf2x32(uint32_t k0, uint32_t k1,
                                       uint32_t x0, uint32_t x1,
                                       uint32_t& o0, uint32_t& o1) {
  uint32_t ks2 = k0 ^ k1 ^ 0x1BD11BDAu;
  x0 += k0; x1 += k1;
#define TFR(r) { x0 += x1; x1 = (x1 << r) | (x1 >> (32 - r)); x1 ^= x0; }
  TFR(13) TFR(15) TFR(26) TFR(6)
  x0 += k1;  x1 += ks2 + 1u;
  TFR(17) TFR(29) TFR(16) TFR(24)
  x0 += ks2; x1 += k0 + 2u;
  TFR(13) TFR(15) TFR(26) TFR(6)
  x0 += k0;  x1 += k1 + 3u;
  TFR(17) TFR(29) TFR(16) TFR(24)
  x0 += k1;  x1 += ks2 + 4u;
  TFR(13) TFR(15) TFR(26) TFR(6)
  x0 += ks2; x1 += k0 + 5u;
#undef TFR
  o0 = x0; o1 = x1;
}

// XLA CPU's log.f32 (Cephes/Eigen-3.3 plog), strict f32 mul/add, no FMA.
// Bit-exact vs reference (verified R3-R8: absmax 0.094 << 0.259).
__device__ __forceinline__ float xla_cpu_log_f32(float s) {
  uint32_t bits = __float_as_uint(s);
  int emm0 = (int)(bits >> 23) - 0x7f;
  float e = __fadd_rn((float)emm0, 1.0f);
  float m = __uint_as_float((bits & 0x007fffffu) | 0x3f000000u);
  bool mlt = m < 0.70710677f;
  float tmp = mlt ? m : 0.0f;
  float x = __fsub_rn(m, 1.0f);
  e = __fsub_rn(e, mlt ? 1.0f : 0.0f);
  x = __fadd_rn(x, tmp);
  float x2 = __fmul_rn(x, x);
  float x3 = __fmul_rn(x2, x);
  float y, y1, y2;
  y  = __fadd_rn(__fmul_rn(7.0376836292e-2f,  x), -1.1514610310e-1f);
  y1 = __fadd_rn(__fmul_rn(-1.2420140846e-1f, x),  1.4249322787e-1f);
  y2 = __fadd_rn(__fmul_rn(2.0000714765e-1f,  x), -2.4999993993e-1f);
  y  = __fadd_rn(__fmul_rn(y,  x),  1.1676998740e-1f);
  y1 = __fadd_rn(__fmul_rn(y1, x), -1.6668057665e-1f);
  y2 = __fadd_rn(__fmul_rn(y2, x),  3.3333331174e-1f);
  y  = __fadd_rn(__fmul_rn(y, x3), y1);
  y  = __fadd_rn(__fmul_rn(y, x3), y2);
  y  = __fmul_rn(y, x3);
  y1 = __fmul_rn(e, -2.12194440e-4f);
  tmp = __fmul_rn(x2, 0.5f);
  y  = __fadd_rn(y, y1);
  x  = __fsub_rn(x, tmp);
  y2 = __fmul_rn(e, 0.693359375f);
  x  = __fadd_rn(x, y);
  x  = __fadd_rn(x, y2);
  return x;
}

// XLA EmitErfInv f32 (Giles): w = -log((1-x)*(1+x)), branch at w<5.
// Branchy on purpose: ~80% of wave-steps skip the far path via execz.
__device__ __forceinline__ float xla_erfinv_f32(float x) {
  float s = __fmul_rn(__fsub_rn(1.0f, x), __fadd_rn(1.0f, x));
  float w = -xla_cpu_log_f32(s);
  float p;
  if (w < 5.0f) {
    float v = __fsub_rn(w, 2.5f);
    p = 2.81022636e-08f;
    p = __fadd_rn(__fmul_rn(p, v), 3.43273939e-07f);
    p = __fadd_rn(__fmul_rn(p, v), -3.5233877e-06f);
    p = __fadd_rn(__fmul_rn(p, v), -4.39150654e-06f);
    p = __fadd_rn(__fmul_rn(p, v), 0.00021858087f);
    p = __fadd_rn(__fmul_rn(p, v), -0.00125372503f);
    p = __fadd_rn(__fmul_rn(p, v), -0.00417768164f);
    p = __fadd_rn(__fmul_rn(p, v), 0.246640727f);
    p = __fadd_rn(__fmul_rn(p, v), 1.50140941f);
  } else {
    float v = __fsub_rn(__fsqrt_rn(w), 3.0f);
    p = -0.000200214257f;
    p = __fadd_rn(__fmul_rn(p, v), 0.000100950558f);
    p = __fadd_rn(__fmul_rn(p, v), 0.00134934322f);
    p = __fadd_rn(__fmul_rn(p, v), -0.00367342844f);
    p = __fadd_rn(__fmul_rn(p, v), 0.00573950773f);
    p = __fadd_rn(__fmul_rn(p, v), -0.0076224613f);
    p = __fadd_rn(__fmul_rn(p, v), 0.00943887047f);
    p = __fadd_rn(__fmul_rn(p, v), 1.00167406f);
    p = __fadd_rn(__fmul_rn(p, v), 2.83297682f);
  }
  return __fmul_rn(p, x);
}

__device__ __forceinline__ float normal_from_bits(uint32_t bits) {
  const float MINVAL = __uint_as_float(0xBF7FFFFFu);   // nextafter(-1,0)
  float f = __uint_as_float((bits >> 9) | 0x3F800000u) - 1.0f;
  float u = __fadd_rn(__fmul_rn(f, 2.0f), MINVAL);
  u = fmaxf(MINVAL, u);
  const float SQRT2 = __uint_as_float(0x3FB504F3u);
  return __fmul_rn(SQRT2, xla_erfinv_f32(u));
}

// Persistent kernel, per-lane t. Counter-based RNG => lanes in one wave may
// sit at different t; all 3000 step keys live in LDS (per-lane gather, ~2-4
// way bank aliasing — cheap per m136). Dead lanes refill from one global
// atomic pool every KREFILL steps (one atomicAdd per wave). When the pool is
// dry, the wave switches to scan-drain: one walker at a time, 64 parallel
// q's + exact sequential shfl-scan (proven R5/R6 tail logic).
__global__ __launch_bounds__(BLOCK)
void ddm_persist(const float* __restrict__ sv_p, const float* __restrict__ rate_p,
                 const float* __restrict__ ndt_p, const float* __restrict__ thr_p,
                 const float* __restrict__ noise_p, const float* __restrict__ dt_p,
                 const int* __restrict__ nw_p, float* __restrict__ out) {
  __shared__ uint2 skeys[NSTEPS];
  for (int t = threadIdx.x; t < NSTEPS; t += BLOCK) {
    uint32_t a, b;
    tf2x32(0u, 0u, 0u, (uint32_t)t, a, b);
    skeys[t] = make_uint2(a, b);
  }
  __syncthreads();

  int nw = *nw_p;
  float sv = *sv_p, rate = *rate_p, ndt = *ndt_p, thr = *thr_p,
        noise = *noise_p, dt = *dt_p;
  float rate_dt = __fmul_rn(rate, dt);
  float sqrt_dt = __fsqrt_rn(dt);
  float p0 = __fadd_rn(0.0f, sv);        // zeros + starting_value
  int lane = threadIdx.x & 63;

  int i = blockIdx.x * BLOCK + threadIdx.x;   // static first walker
  float p = p0;
  int t = 0;
  bool alive = (i < nw);
  bool dry = false;

  // ---- phase 1: per-lane walkers, periodic refill ----
  while (!dry) {
    for (int s = 0; s < KREFILL; ++s) {
      if (alive) {                       // R6-proven branchy body (~130 VALU)
        uint2 k = skeys[t];              // per-lane t: LDS gather
        uint32_t b1, b2;
        tf2x32(k.x, k.y, 0u, (uint32_t)i, b1, b2);
        float z = normal_from_bits(b1 ^ b2);
        p = __fadd_rn(p, __fmul_rn(__fadd_rn(rate_dt, __fmul_rn(noise, z)), sqrt_dt));
        ++t;
        bool cross = !(fabsf(p) < thr);
        if (cross | (t >= NSTEPS)) {     // rts count == t in both cases
          out[i] = __fadd_rn(ndt, __fmul_rn((float)t, dt));
          out[nw + i] = (p <= -thr) ? 0.0f : 1.0f;
          alive = false;
        }
      }
    }
    uint64_t need = __ballot(!alive);
    if (need != 0ull) {
      uint32_t cnt = (uint32_t)__popcll(need);
      int leader = __ffsll((unsigned long long)need) - 1;
      uint32_t base = 0;
      if (lane == leader) base = atomicAdd(&g_pool, cnt);
      base = (uint32_t)__shfl((int)base, leader);
      if (!alive) {
        uint32_t myid = base + (uint32_t)__popcll(need & ((1ull << lane) - 1ull));
        if (myid < (uint32_t)nw) { i = (int)myid; p = p0; t = 0; alive = true; }
      }
      dry = (base + cnt > (uint32_t)nw);  // wave-uniform (base,cnt uniform)
    }
  }

  // ---- drain: scan-mode, one walker per wave, pool is dry ----
  uint64_t m;
  while ((m = __ballot(alive)) != 0ull) {
    int L = __ffsll((unsigned long long)m) - 1;
    int wi = __shfl(i, L);
    float wp = __shfl(p, L);
    int wt = __shfl(t, L);
    int rts_i = NSTEPS;
    bool done = false;
    while (!done) {
      int valid = NSTEPS - wt; if (valid > 64) valid = 64;
      if (valid <= 0) break;             // safety (alive implies wt<NSTEPS)
      int tl = wt + (lane < valid ? lane : valid - 1);
      uint2 kk = skeys[tl];              // consecutive t: 2-way LDS, free
      uint32_t b1, b2;
      tf2x32(kk.x, kk.y, 0u, (uint32_t)wi, b1, b2);
      float z = normal_from_bits(b1 ^ b2);
      float q = __fmul_rn(__fadd_rn(rate_dt, __fmul_rn(noise, z)), sqrt_dt);
      for (int j = 0; j < valid; ++j) {  // exact sequential scan (uniform)
        float qj = __shfl(q, j);
        wp = __fadd_rn(wp, qj);
        if (!(fabsf(wp) < thr)) { rts_i = wt + j + 1; done = true; break; }
      }
      if (!done) {
        wt += valid;
        if (wt >= NSTEPS) done = true;   // ran out the clock: rts = 3000
      }
    }
    if (lane == L) {
      out[wi] = __fadd_rn(ndt, __fmul_rn((float)rts_i, dt));
      out[nw + wi] = (wp <= -thr) ? 0.0f : 1.0f;
      alive = false;                     // retire this wave's walker
    }
  }
}

extern "C" void kernel_launch(void* const* d_in, const int* in_sizes, int n_in,
                              void* d_out, int out_size, void* d_ws, size_t ws_size,
                              hipStream_t stream) {
  const float* sv    = (const float*)d_in[0];
  const float* rate  = (const float*)d_in[1];
  const float* ndt   = (const float*)d_in[2];
  const float* thr   = (const float*)d_in[3];
  const float* noise = (const float*)d_in[4];
  const float* dt    = (const float*)d_in[5];
  const int*   nw    = (const int*)d_in[6];
  float* out = (float*)d_out;

  init_kernel<<<1, 1, 0, stream>>>();
  ddm_persist<<<NBP, BLOCK, 0, stream>>>(sv, rate, ndt, thr, noise, dt, nw, out);
}

// Round 10
// 811.683 us; speedup vs baseline: 4.1256x; 4.1256x over previous
//
#include <hip/hip_runtime.h>
#include <math.h>

// hipcc defaults to -ffp-contract=fast; contraction would fuse mul+add into
// FMA and break bit-exactness vs XLA. Scalar helpers use __fmul_rn/__fadd_rn.
#pragma clang fp contract(off)

#define NSTEPS 3000
#define NWALK  1048576
#define BLOCK  256
#define WPB    512              // walkers per block
#define NBLK   (NWALK / WPB)    // 2048 independent blocks (8/CU, one cohort)
#define CHUNK  64
#define MAXR   46               // 46*64 = 2944 < 3000; drain caps at 3000
#define DRAIN  48               // below this, scan-drain beats dense stepping

// Threefry-2x32, 20 rounds, exactly JAX's schedule.
__device__ __forceinline__ void tf2x32(uint32_t k0, uint32_t k1,
                                       uint32_t x0, uint32_t x1,
                                       uint32_t& o0, uint32_t& o1) {
  uint32_t ks2 = k0 ^ k1 ^ 0x1BD11BDAu;
  x0 += k0; x1 += k1;
#define TFR(r) { x0 += x1; x1 = (x1 << r) | (x1 >> (32 - r)); x1 ^= x0; }
  TFR(13) TFR(15) TFR(26) TFR(6)
  x0 += k1;  x1 += ks2 + 1u;
  TFR(17) TFR(29) TFR(16) TFR(24)
  x0 += ks2; x1 += k0 + 2u;
  TFR(13) TFR(15) TFR(26) TFR(6)
  x0 += k0;  x1 += k1 + 3u;
  TFR(17) TFR(29) TFR(16) TFR(24)
  x0 += k1;  x1 += ks2 + 4u;
  TFR(13) TFR(15) TFR(26) TFR(6)
  x0 += ks2; x1 += k0 + 5u;
#undef TFR
  o0 = x0; o1 = x1;
}

// XLA CPU's log.f32 (Cephes/Eigen-3.3 plog), strict f32 mul/add, no FMA.
// Bit-exact vs reference (verified R3-R9: absmax 0.094 << 0.259).
__device__ __forceinline__ float xla_cpu_log_f32(float s) {
  uint32_t bits = __float_as_uint(s);
  int emm0 = (int)(bits >> 23) - 0x7f;
  float e = __fadd_rn((float)emm0, 1.0f);
  float m = __uint_as_float((bits & 0x007fffffu) | 0x3f000000u);
  bool mlt = m < 0.70710677f;
  float tmp = mlt ? m : 0.0f;
  float x = __fsub_rn(m, 1.0f);
  e = __fsub_rn(e, mlt ? 1.0f : 0.0f);
  x = __fadd_rn(x, tmp);
  float x2 = __fmul_rn(x, x);
  float x3 = __fmul_rn(x2, x);
  float y, y1, y2;
  y  = __fadd_rn(__fmul_rn(7.0376836292e-2f,  x), -1.1514610310e-1f);
  y1 = __fadd_rn(__fmul_rn(-1.2420140846e-1f, x),  1.4249322787e-1f);
  y2 = __fadd_rn(__fmul_rn(2.0000714765e-1f,  x), -2.4999993993e-1f);
  y  = __fadd_rn(__fmul_rn(y,  x),  1.1676998740e-1f);
  y1 = __fadd_rn(__fmul_rn(y1, x), -1.6668057665e-1f);
  y2 = __fadd_rn(__fmul_rn(y2, x),  3.3333331174e-1f);
  y  = __fadd_rn(__fmul_rn(y, x3), y1);
  y  = __fadd_rn(__fmul_rn(y, x3), y2);
  y  = __fmul_rn(y, x3);
  y1 = __fmul_rn(e, -2.12194440e-4f);
  tmp = __fmul_rn(x2, 0.5f);
  y  = __fadd_rn(y, y1);
  x  = __fsub_rn(x, tmp);
  y2 = __fmul_rn(e, 0.693359375f);
  x  = __fadd_rn(x, y);
  x  = __fadd_rn(x, y2);
  return x;
}

// XLA EmitErfInv f32 (Giles): w = -log((1-x)*(1+x)), branch at w<5.
__device__ __forceinline__ float xla_erfinv_f32(float x) {
  float s = __fmul_rn(__fsub_rn(1.0f, x), __fadd_rn(1.0f, x));
  float w = -xla_cpu_log_f32(s);
  float p;
  if (w < 5.0f) {
    float v = __fsub_rn(w, 2.5f);
    p = 2.81022636e-08f;
    p = __fadd_rn(__fmul_rn(p, v), 3.43273939e-07f);
    p = __fadd_rn(__fmul_rn(p, v), -3.5233877e-06f);
    p = __fadd_rn(__fmul_rn(p, v), -4.39150654e-06f);
    p = __fadd_rn(__fmul_rn(p, v), 0.00021858087f);
    p = __fadd_rn(__fmul_rn(p, v), -0.00125372503f);
    p = __fadd_rn(__fmul_rn(p, v), -0.00417768164f);
    p = __fadd_rn(__fmul_rn(p, v), 0.246640727f);
    p = __fadd_rn(__fmul_rn(p, v), 1.50140941f);
  } else {
    float v = __fsub_rn(__fsqrt_rn(w), 3.0f);
    p = -0.000200214257f;
    p = __fadd_rn(__fmul_rn(p, v), 0.000100950558f);
    p = __fadd_rn(__fmul_rn(p, v), 0.00134934322f);
    p = __fadd_rn(__fmul_rn(p, v), -0.00367342844f);
    p = __fadd_rn(__fmul_rn(p, v), 0.00573950773f);
    p = __fadd_rn(__fmul_rn(p, v), -0.0076224613f);
    p = __fadd_rn(__fmul_rn(p, v), 0.00943887047f);
    p = __fadd_rn(__fmul_rn(p, v), 1.00167406f);
    p = __fadd_rn(__fmul_rn(p, v), 2.83297682f);
  }
  return __fmul_rn(p, x);
}

__device__ __forceinline__ float normal_from_bits(uint32_t bits) {
  const float MINVAL = __uint_as_float(0xBF7FFFFFu);   // nextafter(-1,0)
  float f = __uint_as_float((bits >> 9) | 0x3F800000u) - 1.0f;
  float u = __fadd_rn(__fmul_rn(f, 2.0f), MINVAL);
  u = fmaxf(MINVAL, u);
  const float SQRT2 = __uint_as_float(0x3FB504F3u);
  return __fmul_rn(SQRT2, xla_erfinv_f32(u));
}

// Block-local compaction, single launch. Each block owns walkers
// [b*512, b*512+512). Dense rounds (wave-uniform t, R6-proven body, LDS
// broadcast keys) with LDS ping-pong compaction between rounds; below
// DRAIN survivors, switch to scan-drain (one walker per wave, 64 parallel
// q's + exact sequential shfl-scan, keys recomputed inline per lane).
// Blocks are fully independent: no global state, no launch sequence.
__global__ __launch_bounds__(BLOCK)
void ddm_block(const float* __restrict__ sv_p, const float* __restrict__ rate_p,
               const float* __restrict__ ndt_p, const float* __restrict__ thr_p,
               const float* __restrict__ noise_p, const float* __restrict__ dt_p,
               const int* __restrict__ nw_p, float* __restrict__ out) {
  __shared__ uint2 skeys[CHUNK];
  __shared__ unsigned short l_lid[2][WPB];
  __shared__ float l_pv[2][WPB];
  __shared__ int scnt;

  int nw = *nw_p;
  float sv = *sv_p, rate = *rate_p, ndt = *ndt_p, thr = *thr_p,
        noise = *noise_p, dt = *dt_p;
  float rate_dt = __fmul_rn(rate, dt);
  float sqrt_dt = __fsqrt_rn(dt);
  float p0 = __fadd_rn(0.0f, sv);        // zeros + starting_value

  int tid = threadIdx.x;
  int lane = tid & 63;
  int base = blockIdx.x * WPB;

  int count = WPB;
  int cur = 0;
  int t0 = 0;
  if (tid == 0) scnt = 0;

  // ---- Phase A: dense rounds with block-local compaction ----
  for (int r = 0; r < MAXR && count >= DRAIN; ++r) {
    if (tid < CHUNK) {                   // stage this round's keys
      uint32_t a, b;
      tf2x32(0u, 0u, 0u, (uint32_t)(t0 + tid), a, b);
      skeys[tid] = make_uint2(a, b);
    }
    __syncthreads();                     // keys + scnt reset visible

    for (int slot = tid; slot < count; slot += BLOCK) {
      int lid; float p;
      if (r == 0) { lid = slot; p = p0; }
      else { lid = (int)l_lid[cur][slot]; p = l_pv[cur][slot]; }
      int ii = base + lid;
      if (ii >= nw) continue;            // robustness (nw fixed at 1M by setup)
      bool alive = true;

      for (int s = 0; s < CHUNK; ++s) {  // R6-proven branchy dense body
        if (alive) {
          uint2 k = skeys[s];            // wave-uniform: LDS broadcast
          uint32_t b1, b2;
          tf2x32(k.x, k.y, 0u, (uint32_t)ii, b1, b2);
          float z = normal_from_bits(b1 ^ b2);
          p = __fadd_rn(p, __fmul_rn(__fadd_rn(rate_dt, __fmul_rn(noise, z)), sqrt_dt));
          if (!(fabsf(p) < thr)) {
            float rts = (float)(t0 + s + 1);   // exact int == accumulated +1.0f
            out[ii] = __fadd_rn(ndt, __fmul_rn(rts, dt));
            out[nw + ii] = (p <= -thr) ? 0.0f : 1.0f;
            alive = false;
          }
        }
      }

      uint64_t m = __ballot(alive);      // among lanes active in this iter
      if (m != 0ull) {                   // one LDS atomic per wave
        int leader = __ffsll((unsigned long long)m) - 1;
        int bpos = 0;
        if (lane == leader) bpos = atomicAdd(&scnt, (int)__popcll(m));
        bpos = __shfl(bpos, leader);
        if (alive) {
          int pos = bpos + (int)__popcll(m & ((1ull << lane) - 1ull));
          l_lid[cur ^ 1][pos] = (unsigned short)lid;
          l_pv[cur ^ 1][pos] = p;
        }
      }
    }
    __syncthreads();                     // all appends done
    count = scnt; cur ^= 1; t0 += CHUNK; // every thread reads scnt
    __syncthreads();                     // all have read scnt
    if (tid == 0) scnt = 0;              // reset for next round (C barrier above)
  }

  // ---- Phase B: scan-drain, one walker per wave (no barriers) ----
  int wave_id = tid >> 6;
  for (int k = wave_id; k < count; k += (BLOCK / 64)) {
    int lid = (int)l_lid[cur][k];        // same addr all lanes: broadcast
    float p = l_pv[cur][k];
    int ii = base + lid;
    if (ii >= nw) continue;
    int wt = t0;
    int rts_i = NSTEPS;
    bool done = false;
    while (!done) {
      int valid = NSTEPS - wt; if (valid > 64) valid = 64;
      if (valid <= 0) break;
      int tl = wt + (lane < valid ? lane : valid - 1);
      uint32_t ka, kb, b1, b2;
      tf2x32(0u, 0u, 0u, (uint32_t)tl, ka, kb);   // key inline (no LDS dep)
      tf2x32(ka, kb, 0u, (uint32_t)ii, b1, b2);
      float z = normal_from_bits(b1 ^ b2);
      float q = __fmul_rn(__fadd_rn(rate_dt, __fmul_rn(noise, z)), sqrt_dt);
      for (int j = 0; j < valid; ++j) {  // exact sequential scan (uniform)
        float qj = __shfl(q, j);
        p = __fadd_rn(p, qj);
        if (!(fabsf(p) < thr)) { rts_i = wt + j + 1; done = true; break; }
      }
      if (!done) {
        wt += valid;
        if (wt >= NSTEPS) done = true;   // ran out the clock: rts = 3000
      }
    }
    if (lane == 0) {
      out[ii] = __fadd_rn(ndt, __fmul_rn((float)rts_i, dt));
      out[nw + ii] = (p <= -thr) ? 0.0f : 1.0f;
    }
  }
}

extern "C" void kernel_launch(void* const* d_in, const int* in_sizes, int n_in,
                              void* d_out, int out_size, void* d_ws, size_t ws_size,
                              hipStream_t stream) {
  const float* sv    = (const float*)d_in[0];
  const float* rate  = (const float*)d_in[1];
  const float* ndt   = (const float*)d_in[2];
  const float* thr   = (const float*)d_in[3];
  const float* noise = (const float*)d_in[4];
  const float* dt    = (const float*)d_in[5];
  const int*   nw    = (const int*)d_in[6];
  float* out = (float*)d_out;

  ddm_block<<<NBLK, BLOCK, 0, stream>>>(sv, rate, ndt, thr, noise, dt, nw, out);
}